// Round 1
// baseline (119.741 us; speedup 1.0000x reference)
//
#include <hip/hip_runtime.h>

#define TWO_N 400
#define IN_C 32
#define OUT_C 32
#define NG 4
#define NB 512

// Kernel 1: recover inverse permutation indices from the permutation matrices.
// inv[g*TWO_N + o] = i such that perm[g,i,o] == 1   (so x[...,inv] feeds output o)
__global__ __launch_bounds__(256) void build_inv_kernel(
        const float* __restrict__ perm, int* __restrict__ inv) {
    int t = blockIdx.x * blockDim.x + threadIdx.x;
    if (t >= NG * TWO_N) return;
    int g = t / TWO_N;
    int o = t - g * TWO_N;
    const float* p = perm + (size_t)g * TWO_N * TWO_N + o;
    int found = 0;
    for (int i = 0; i < TWO_N; ++i) {
        // coalesced across lanes: consecutive o -> consecutive addresses
        if (p[(size_t)i * TWO_N] > 0.5f) found = i;
    }
    inv[t] = found;
}

// Kernel 2: one thread per (b, o); 32 fp32 accumulators (one per output channel d).
// out[b,d,o] = sum_g sum_c x[b,c,inv_g(o)] * w[g,c,d]
// Weight indices are wave-uniform -> compiler emits scalar (s_load) reads.
// x reads: consecutive o -> consecutive inv_g(o) -> contiguous per-wave segments.
__global__ __launch_bounds__(256) void dihedral_conv_kernel(
        const float* __restrict__ x,
        const float* __restrict__ w,
        const int*   __restrict__ inv,
        float*       __restrict__ out) {
    int idx = blockIdx.x * blockDim.x + threadIdx.x;   // [0, NB*TWO_N)
    int b = idx / TWO_N;
    int o = idx - b * TWO_N;

    const float* xb = x + (size_t)b * IN_C * TWO_N;

    float acc[OUT_C];
#pragma unroll
    for (int d = 0; d < OUT_C; ++d) acc[d] = 0.0f;

    for (int g = 0; g < NG; ++g) {
        int iv = inv[g * TWO_N + o];            // coalesced int load
        const float* xp = xb + iv;
        const float* wp = w + g * IN_C * OUT_C; // wave-uniform base
#pragma unroll
        for (int c = 0; c < IN_C; ++c) {
            float xv = xp[(size_t)c * TWO_N];   // contiguous across lanes
#pragma unroll
            for (int d = 0; d < OUT_C; ++d) {
                acc[d] = fmaf(xv, wp[c * OUT_C + d], acc[d]);
            }
        }
    }

    float* op = out + (size_t)b * OUT_C * TWO_N + o;
#pragma unroll
    for (int d = 0; d < OUT_C; ++d) op[(size_t)d * TWO_N] = acc[d];
}

extern "C" void kernel_launch(void* const* d_in, const int* in_sizes, int n_in,
                              void* d_out, int out_size, void* d_ws, size_t ws_size,
                              hipStream_t stream) {
    const float* x    = (const float*)d_in[0];  // [512, 32, 400]
    const float* w    = (const float*)d_in[1];  // [4, 32, 32]
    const float* perm = (const float*)d_in[2];  // [4, 400, 400]
    float* out = (float*)d_out;                 // [512, 32, 400]
    int* inv = (int*)d_ws;                      // NG*TWO_N ints

    build_inv_kernel<<<(NG * TWO_N + 255) / 256, 256, 0, stream>>>(perm, inv);

    int total = NB * TWO_N;                     // 204800
    dihedral_conv_kernel<<<total / 256, 256, 0, stream>>>(x, w, inv, out);
}

// Round 2
// 116.882 us; speedup vs baseline: 1.0245x; 1.0245x over previous
//
#include <hip/hip_runtime.h>

#define TWO_N 400
#define IN_C 32
#define OUT_C 32
#define NG 4
#define NB 512

// Kernel 1: recover inverse permutation indices from the permutation matrices.
// One thread per (g,i,o) matrix element, fully coalesced read of perm;
// exactly one element per (g,o) column is 1.0 -> that lane writes inv[g,o]=i.
__global__ __launch_bounds__(256) void build_inv_kernel(
        const float* __restrict__ perm, int* __restrict__ inv) {
    int t = blockIdx.x * blockDim.x + threadIdx.x;   // [0, NG*TWO_N*TWO_N)
    if (t >= NG * TWO_N * TWO_N) return;
    float v = perm[t];                               // coalesced
    if (v > 0.5f) {
        int g = t / (TWO_N * TWO_N);
        int rem = t - g * (TWO_N * TWO_N);
        int i = rem / TWO_N;
        int o = rem - i * TWO_N;
        inv[g * TWO_N + o] = i;                      // unique writer per slot
    }
}

// Kernel 2: one thread per (b, o); 32 fp32 accumulators (one per output channel d).
// out[b,d,o] = sum_g sum_c x[b,c,inv_g(o)] * w[g,c,d]
// Weight indices are wave-uniform -> scalar (s_load) reads via constant cache.
// x reads: consecutive o -> consecutive inv_g(o) -> contiguous per-wave segments.
__global__ __launch_bounds__(256) void dihedral_conv_kernel(
        const float* __restrict__ x,
        const float* __restrict__ w,
        const int*   __restrict__ inv,
        float*       __restrict__ out) {
    int idx = blockIdx.x * blockDim.x + threadIdx.x;   // [0, NB*TWO_N)
    int b = idx / TWO_N;
    int o = idx - b * TWO_N;

    const float* xb = x + (size_t)b * IN_C * TWO_N;

    // Prefetch all 4 gather indices up front (independent loads in flight).
    int iv0 = inv[0 * TWO_N + o];
    int iv1 = inv[1 * TWO_N + o];
    int iv2 = inv[2 * TWO_N + o];
    int iv3 = inv[3 * TWO_N + o];
    int ivs[NG] = {iv0, iv1, iv2, iv3};

    float acc[OUT_C];
#pragma unroll
    for (int d = 0; d < OUT_C; ++d) acc[d] = 0.0f;

#pragma unroll
    for (int g = 0; g < NG; ++g) {
        const float* xp = xb + ivs[g];
        const float* wp = w + g * IN_C * OUT_C;  // wave-uniform base
#pragma unroll
        for (int c = 0; c < IN_C; ++c) {
            float xv = xp[(size_t)c * TWO_N];    // contiguous across lanes
#pragma unroll
            for (int d = 0; d < OUT_C; ++d) {
                acc[d] = fmaf(xv, wp[c * OUT_C + d], acc[d]);
            }
        }
    }

    float* op = out + (size_t)b * OUT_C * TWO_N + o;
#pragma unroll
    for (int d = 0; d < OUT_C; ++d) {
        __builtin_nontemporal_store(acc[d], op + (size_t)d * TWO_N);
    }
}

extern "C" void kernel_launch(void* const* d_in, const int* in_sizes, int n_in,
                              void* d_out, int out_size, void* d_ws, size_t ws_size,
                              hipStream_t stream) {
    const float* x    = (const float*)d_in[0];  // [512, 32, 400]
    const float* w    = (const float*)d_in[1];  // [4, 32, 32]
    const float* perm = (const float*)d_in[2];  // [4, 400, 400]
    float* out = (float*)d_out;                 // [512, 32, 400]
    int* inv = (int*)d_ws;                      // NG*TWO_N ints

    int total_p = NG * TWO_N * TWO_N;           // 640000
    build_inv_kernel<<<(total_p + 255) / 256, 256, 0, stream>>>(perm, inv);

    int total = NB * TWO_N;                     // 204800
    dihedral_conv_kernel<<<total / 256, 256, 0, stream>>>(x, w, inv, out);
}

// Round 3
// 116.814 us; speedup vs baseline: 1.0251x; 1.0006x over previous
//
#include <hip/hip_runtime.h>

#define TWO_N 400
#define IN_C 32
#define OUT_C 32
#define NG 4
#define NB 512
#define BLK 448   // 7 waves; lanes 0..399 compute, all lanes help stage LDS

// Kernel 1: recover inverse permutation indices from the permutation matrices.
// One thread per (g,i,o) element, fully coalesced; the unique lane seeing 1.0
// writes inv[g,o] = i.
__global__ __launch_bounds__(256) void build_inv_kernel(
        const float* __restrict__ perm, int* __restrict__ inv) {
    int t = blockIdx.x * blockDim.x + threadIdx.x;   // [0, NG*TWO_N*TWO_N)
    if (t >= NG * TWO_N * TWO_N) return;
    float v = perm[t];                               // coalesced
    if (v > 0.5f) {
        int g = t / (TWO_N * TWO_N);
        int rem = t - g * (TWO_N * TWO_N);
        int i = rem / TWO_N;
        int o = rem - i * TWO_N;
        inv[g * TWO_N + o] = i;                      // unique writer per slot
    }
}

// Kernel 2: one block per b. Stage x[b] (32x400 f32 = 51.2 KB) in LDS, then
// thread o accumulates 32 output channels:
//   out[b,d,o] = sum_g sum_c xs[c, inv_g(o)] * w[g,c,d]
// LDS reads: consecutive lanes -> consecutive (or reversed) addresses ->
// <=2 lanes/bank -> conflict-free. Weights are wave-uniform -> SGPR loads.
__global__ __launch_bounds__(BLK) void dihedral_conv_kernel(
        const float* __restrict__ x,
        const float* __restrict__ w,
        const int*   __restrict__ inv,
        float*       __restrict__ out) {
    __shared__ float xs[IN_C * TWO_N];               // 51.2 KB

    const int b = blockIdx.x;
    const float* xb = x + (size_t)b * IN_C * TWO_N;

    // Cooperative staging: 3200 float4, coalesced.
    const float4* src4 = (const float4*)xb;
    float4* dst4 = (float4*)xs;
    for (int i = threadIdx.x; i < IN_C * TWO_N / 4; i += BLK)
        dst4[i] = src4[i];
    __syncthreads();

    const int o = threadIdx.x;
    if (o < TWO_N) {
        // Prefetch all 4 gather indices (independent loads).
        int ivs[NG];
#pragma unroll
        for (int g = 0; g < NG; ++g) ivs[g] = inv[g * TWO_N + o];

        float acc[OUT_C];
#pragma unroll
        for (int d = 0; d < OUT_C; ++d) acc[d] = 0.0f;

#pragma unroll
        for (int g = 0; g < NG; ++g) {
            const float* wp = w + g * IN_C * OUT_C;  // wave-uniform base
            const float* xp = xs + ivs[g];
#pragma unroll
            for (int c = 0; c < IN_C; ++c) {
                float xv = xp[c * TWO_N];            // ds_read_b32, conflict-free
#pragma unroll
                for (int d = 0; d < OUT_C; ++d)
                    acc[d] = fmaf(xv, wp[c * OUT_C + d], acc[d]);
            }
        }

        float* op = out + (size_t)b * OUT_C * TWO_N + o;
#pragma unroll
        for (int d = 0; d < OUT_C; ++d)
            __builtin_nontemporal_store(acc[d], op + (size_t)d * TWO_N);
    }
}

extern "C" void kernel_launch(void* const* d_in, const int* in_sizes, int n_in,
                              void* d_out, int out_size, void* d_ws, size_t ws_size,
                              hipStream_t stream) {
    const float* x    = (const float*)d_in[0];  // [512, 32, 400]
    const float* w    = (const float*)d_in[1];  // [4, 32, 32]
    const float* perm = (const float*)d_in[2];  // [4, 400, 400]
    float* out = (float*)d_out;                 // [512, 32, 400]
    int* inv = (int*)d_ws;                      // NG*TWO_N ints

    int total_p = NG * TWO_N * TWO_N;           // 640000
    build_inv_kernel<<<(total_p + 255) / 256, 256, 0, stream>>>(perm, inv);

    dihedral_conv_kernel<<<NB, BLK, 0, stream>>>(x, w, inv, out);
}

// Round 4
// 89.623 us; speedup vs baseline: 1.3360x; 1.3034x over previous
//
#include <hip/hip_runtime.h>

#define TWO_N 400
#define IN_C 32
#define OUT_C 32
#define NG 4
#define NB 512

// MFMA fragment types per guide (§3): 8 bf16 in 4 VGPRs as short8; 4 fp32 acc.
typedef __attribute__((ext_vector_type(8))) short bf16x8;
typedef __attribute__((ext_vector_type(4))) float f32x4;

// Round-to-nearest-even f32 -> bf16 (branchless).
static __device__ inline unsigned short f2bf(float f) {
    unsigned u = __float_as_uint(f);
    u = (u + 0x7FFFu + ((u >> 16) & 1u)) >> 16;
    return (unsigned short)u;
}

// Kernel 1: recover inverse permutation indices from the permutation matrices.
// One thread per (g,i,o) element, fully coalesced; the unique lane seeing 1.0
// writes inv[g,o] = i.
__global__ __launch_bounds__(256) void build_inv_kernel(
        const float* __restrict__ perm, int* __restrict__ inv) {
    int t = blockIdx.x * blockDim.x + threadIdx.x;   // [0, NG*TWO_N*TWO_N)
    if (t >= NG * TWO_N * TWO_N) return;
    float v = perm[t];                               // coalesced
    if (v > 0.5f) {
        int g = t / (TWO_N * TWO_N);
        int rem = t - g * (TWO_N * TWO_N);
        int i = rem / TWO_N;
        int o = rem - i * TWO_N;
        inv[g * TWO_N + o] = i;                      // unique writer per slot
    }
}

// Kernel 2: one block per b (256 threads = 4 waves). Per-b GEMM via MFMA:
//   out[b, d, o] = sum_{k=(g,c)} w_t[d, k] * x_t[inv_g(o), c]
// A-operand (M=d) from ws[d][k], B-operand (N=o) from xs[i][c] with the
// gather folded into the per-lane LDS address (iv = inv_g(o)).
// xs rows padded to 40 ushorts (80B: 16B-aligned, bank stride 20 -> <=2-way);
// ws rows padded to 136 ushorts (272B: 16B-aligned, bank stride 68 -> <=2-way).
__global__ __launch_bounds__(256) void dihedral_conv_mfma(
        const float* __restrict__ x,
        const float* __restrict__ w,
        const int*   __restrict__ inv,
        float*       __restrict__ out) {
    __shared__ __align__(16) unsigned short xs[TWO_N * 40];   // 32000 B
    __shared__ __align__(16) unsigned short ws[OUT_C * 136];  //  8704 B

    const int t = threadIdx.x;
    const int b = blockIdx.x;
    const float* xb = x + (size_t)b * IN_C * TWO_N;

    // Stage W transposed: ws[d][g*32+c] = bf16(w[g][c][d]). 4096 elems.
#pragma unroll
    for (int r = 0; r < 16; ++r) {
        int f = t + 256 * r;                 // f = g*1024 + c*32 + d
        int d = f & 31;
        int c = (f >> 5) & 31;
        int g = f >> 10;
        ws[d * 136 + g * 32 + c] = f2bf(w[f]);
    }

    // Stage x[b] transposed to bf16: xs[i][c]. Lane covers one i per chunk,
    // 8 consecutive c. Reads: 4x64B segments/instr. Writes: b32, 2-way banks.
    {
        const int il = t >> 2;               // 0..63
        const int cb = (t & 3) * 8;          // 0,8,16,24
        for (int k = 0; k < 7; ++k) {
            int i = il + 64 * k;
            if (i < TWO_N) {
                float v[8];
#pragma unroll
                for (int j = 0; j < 8; ++j) v[j] = xb[(size_t)(cb + j) * TWO_N + i];
                unsigned short* dst = &xs[i * 40 + cb];
#pragma unroll
                for (int j = 0; j < 4; ++j) {
                    unsigned pk = (unsigned)f2bf(v[2 * j]) |
                                  ((unsigned)f2bf(v[2 * j + 1]) << 16);
                    *(unsigned*)(dst + 2 * j) = pk;
                }
            }
        }
    }
    __syncthreads();

    const int lane = t & 63;
    const int wid  = t >> 6;                 // 0..3
    const int l15  = lane & 15;
    const int q    = lane >> 4;              // 0..3
    const int q8   = q * 8;

    // 50 output tiles: T = ot*2 + dt  (ot in [0,25), dt in [0,2))
    for (int T = wid; T < 50; T += 4) {
        int ot = T >> 1;
        int dt = T & 1;
        int o  = ot * 16 + l15;

        int iv0 = inv[0 * TWO_N + o];
        int iv1 = inv[1 * TWO_N + o];
        int iv2 = inv[2 * TWO_N + o];
        int iv3 = inv[3 * TWO_N + o];

        const unsigned short* wrow = &ws[(dt * 16 + l15) * 136 + q8];

        f32x4 acc = {0.f, 0.f, 0.f, 0.f};
        bf16x8 a0 = *(const bf16x8*)(wrow + 0 * 32);
        bf16x8 b0 = *(const bf16x8*)(&xs[iv0 * 40 + q8]);
        acc = __builtin_amdgcn_mfma_f32_16x16x32_bf16(a0, b0, acc, 0, 0, 0);
        bf16x8 a1 = *(const bf16x8*)(wrow + 1 * 32);
        bf16x8 b1 = *(const bf16x8*)(&xs[iv1 * 40 + q8]);
        acc = __builtin_amdgcn_mfma_f32_16x16x32_bf16(a1, b1, acc, 0, 0, 0);
        bf16x8 a2 = *(const bf16x8*)(wrow + 2 * 32);
        bf16x8 b2 = *(const bf16x8*)(&xs[iv2 * 40 + q8]);
        acc = __builtin_amdgcn_mfma_f32_16x16x32_bf16(a2, b2, acc, 0, 0, 0);
        bf16x8 a3 = *(const bf16x8*)(wrow + 3 * 32);
        bf16x8 b3 = *(const bf16x8*)(&xs[iv3 * 40 + q8]);
        acc = __builtin_amdgcn_mfma_f32_16x16x32_bf16(a3, b3, acc, 0, 0, 0);

        // D layout: col(o) = lane&15, row(d) = (lane>>4)*4 + j  [m89 verified]
        float* op = out + (size_t)b * (OUT_C * TWO_N)
                        + (size_t)(dt * 16 + q * 4) * TWO_N + ot * 16 + l15;
#pragma unroll
        for (int j = 0; j < 4; ++j)
            __builtin_nontemporal_store(acc[j], op + (size_t)j * TWO_N);
    }
}

extern "C" void kernel_launch(void* const* d_in, const int* in_sizes, int n_in,
                              void* d_out, int out_size, void* d_ws, size_t ws_size,
                              hipStream_t stream) {
    const float* x    = (const float*)d_in[0];  // [512, 32, 400]
    const float* w    = (const float*)d_in[1];  // [4, 32, 32]
    const float* perm = (const float*)d_in[2];  // [4, 400, 400]
    float* out = (float*)d_out;                 // [512, 32, 400]
    int* inv = (int*)d_ws;                      // NG*TWO_N ints

    int total_p = NG * TWO_N * TWO_N;           // 640000
    build_inv_kernel<<<(total_p + 255) / 256, 256, 0, stream>>>(perm, inv);

    dihedral_conv_mfma<<<NB, 256, 0, stream>>>(x, w, inv, out);
}